// Round 1
// baseline (24.418 us; speedup 1.0000x reference)
//
#include <hip/hip_runtime.h>

#define BB 128
#define TT 512
#define LAG_PENALTY 0.5f

__global__ __launch_bounds__(512) void WeightedLagDenseLoss_kernel(
    const float* __restrict__ pred,
    const float* __restrict__ tgt,
    const float* __restrict__ wts,
    float* __restrict__ out)
{
    __shared__ float s_tgt[TT];
    __shared__ float s_rinv[TT];
    __shared__ float s_part[8];

    const int b = blockIdx.x;
    const int t = threadIdx.x;

    // Stage target row + 1/l table in LDS
    s_tgt[t]  = tgt[b * TT + t];
    s_rinv[t] = (t >= 1) ? (1.0f / (float)t) : 0.0f;
    __syncthreads();

    const float p = pred[b * TT + t];

    // lag_loss = sum_{l=1..511} (1/l) * (p - tgt[min(t+l, 511)])^2
    float acc0 = 0.0f, acc1 = 0.0f;
    #pragma unroll 8
    for (int l = 1; l <= TT - 3; l += 2) {
        int   i0 = min(t + l, TT - 1);
        float d0 = p - s_tgt[i0];
        acc0 = fmaf(s_rinv[l] * d0, d0, acc0);
        int   i1 = min(t + l + 1, TT - 1);
        float d1 = p - s_tgt[i1];
        acc1 = fmaf(s_rinv[l + 1] * d1, d1, acc1);
    }
    {   // l = 511: index min(t+511, 511) == 511 always
        float d = p - s_tgt[TT - 1];
        acc0 = fmaf(s_rinv[TT - 1] * d, d, acc0);
    }
    float lag = acc0 + acc1;

    float dm  = p - s_tgt[t];
    float tot = fmaf(LAG_PENALTY, lag, dm * dm) * wts[b];

    // Scale by exact power-of-two 1/(B*T) = 1/65536, then reduce
    float v = tot * (1.0f / (float)(BB * TT));

    // wave64 shuffle reduction
    for (int off = 32; off > 0; off >>= 1)
        v += __shfl_down(v, off, 64);

    const int wave = t >> 6;
    if ((t & 63) == 0) s_part[wave] = v;
    __syncthreads();

    if (t == 0) {
        float s = 0.0f;
        #pragma unroll
        for (int i = 0; i < 8; ++i) s += s_part[i];
        atomicAdd(out, s);
    }
}

extern "C" void kernel_launch(void* const* d_in, const int* in_sizes, int n_in,
                              void* d_out, int out_size, void* d_ws, size_t ws_size,
                              hipStream_t stream) {
    const float* pred = (const float*)d_in[0];
    const float* tgt  = (const float*)d_in[1];
    const float* wts  = (const float*)d_in[2];
    float* out = (float*)d_out;

    hipMemsetAsync(out, 0, sizeof(float), stream);
    WeightedLagDenseLoss_kernel<<<dim3(BB), dim3(TT), 0, stream>>>(pred, tgt, wts, out);
}